// Round 5
// baseline (2326.243 us; speedup 1.0000x reference)
//
#include <hip/hip_runtime.h>

// RNN B=256 T=2048 I=64 H=256 — one WG/sample, 256 CUs, MFMA matvec.
// Round 5: TWO waves (128 thr), each owning 128 rows = 8 M-tiles. The step
// time has been pinned at ~1400 cyc across R2-R4 regardless of MFMA count or
// LDS traffic => the binding cost is the per-step barrier rendezvous +
// lockstep latency skeleton. Minimize rendezvous width: 2-wave s_barrier.
// gfx950's unified 512-reg VGPR/AGPR file holds W_hh as 64 A-frags (256 regs)
// per wave + W_ih^T prod frags (64 regs). xp = x W_ih^T + b precomputed per
// 16-step block into LDS f32 (R4 trick), consumed as acc init. h f16 in LDS,
// double-buffered; per-step barrier is lgkmcnt-only (global x prefetch stays
// in flight).

static constexpr int nB = 256;
static constexpr int nT = 2048;
static constexpr int nI = 64;
static constexpr int nH = 256;
static constexpr int XPB = 16;        // timesteps per xp block
static constexpr int XPS = nH + 4;    // xp row stride (f32)
static constexpr int THREADS = 128;   // 2 waves; wave w owns rows [128w,128w+128)

typedef _Float16 f16x8 __attribute__((ext_vector_type(8)));
typedef _Float16 f16x2 __attribute__((ext_vector_type(2)));
typedef float f32x4 __attribute__((ext_vector_type(4)));

__device__ __forceinline__ void barrier_lgkm() {
  // LDS-visibility barrier that does NOT drain vmcnt: global x prefetch stays
  // in flight across per-step barriers.
  asm volatile("s_waitcnt lgkmcnt(0)\n\ts_barrier" ::: "memory");
}

__device__ __forceinline__ float fast_tanh(float x) {
  float a = fabsf(x);
  float e = __expf(-2.0f * a);            // in (0,1], never overflows
  float r = (1.0f - e) / (1.0f + e);
  return copysignf(r, x);
}

__global__ __launch_bounds__(THREADS, 1)
void rnn_v5(const float* __restrict__ x, const int* __restrict__ lengths,
            const float* __restrict__ Wih, const float* __restrict__ Whh,
            const float* __restrict__ bih, const float* __restrict__ bhh,
            const float* __restrict__ Wfc, const float* __restrict__ bfc,
            float* __restrict__ out)
{
  __shared__ __align__(16) _Float16 hbuf[2][nH];        // 1 KB
  __shared__ __align__(16) float xpb[2][XPB * XPS];     // 32.5 KB
  __shared__ float red[2];

  const int b   = blockIdx.x;
  const int tid = threadIdx.x;
  const int w   = tid >> 6;       // wave 0..1
  const int l   = tid & 63;
  const int q   = l >> 4;         // quad 0..3
  const int n   = l & 15;         // MFMA column lane
  const int len = lengths[b];     // in [1, nT]
  const float* xb = x + (size_t)b * nT * nI;

  // ---- W_hh A-frags (resident): wave w rows [128w,128w+128) = 8 m-tiles.
  // A layout (16x16x32): lane holds A[m=lane&15][k=8*(lane>>4)+j], j=0..7.
  f16x8 Ah[8][8];                 // 256 VGPRs (unified VGPR/AGPR file)
#pragma unroll
  for (int mt = 0; mt < 8; ++mt) {
    const int row = 128 * w + 16 * mt + n;
#pragma unroll
    for (int kt = 0; kt < 8; ++kt) {
      const float* src = Whh + row * nH + 32 * kt + 8 * q;
      f16x8 a;
#pragma unroll
      for (int j = 0; j < 8; ++j) a[j] = (_Float16)src[j];
      Ah[mt][kt] = a;
    }
  }
  // ---- W_ih^T B-frags for xp production: wave w produces cols [128w,128w+128)
  f16x8 Bp[8][2];                 // 64 VGPRs
  float biasp[8];
#pragma unroll
  for (int c = 0; c < 8; ++c) {
    const int col = 128 * w + 16 * c + n;
#pragma unroll
    for (int kt = 0; kt < 2; ++kt) {
      const float* src = Wih + col * nI + 32 * kt + 8 * q;
      f16x8 a;
#pragma unroll
      for (int j = 0; j < 8; ++j) a[j] = (_Float16)src[j];
      Bp[c][kt] = a;
    }
    biasp[c] = bih[col] + bhh[col];   // bias folded into xp
  }

  // h-write ownership: lane (q,n) owns rows 128w+16*(n&7)+4q+{r0,r0+1}
  const int mtl = n & 7;
  const int r0  = (n >> 3) << 1;
  const int own = 128 * w + 16 * mtl + 4 * q + r0;   // even -> 4B-aligned b32

  // ---- produce xp block 0 (t=0..15); h0 = 0
  {
    const float* pr = xb + (size_t)n * nI + 8 * q;   // A row m=n -> x[t=n]
    float4 x0 = *(const float4*)(pr);
    float4 x1 = *(const float4*)(pr + 4);
    float4 x2 = *(const float4*)(pr + 32);
    float4 x3 = *(const float4*)(pr + 36);
    f16x8 A0 = { (_Float16)x0.x,(_Float16)x0.y,(_Float16)x0.z,(_Float16)x0.w,
                 (_Float16)x1.x,(_Float16)x1.y,(_Float16)x1.z,(_Float16)x1.w };
    f16x8 A1 = { (_Float16)x2.x,(_Float16)x2.y,(_Float16)x2.z,(_Float16)x2.w,
                 (_Float16)x3.x,(_Float16)x3.y,(_Float16)x3.z,(_Float16)x3.w };
#pragma unroll
    for (int c = 0; c < 8; ++c) {
      f32x4 cc = { biasp[c], biasp[c], biasp[c], biasp[c] };
      cc = __builtin_amdgcn_mfma_f32_16x16x32_f16(A0, Bp[c][0], cc, 0, 0, 0);
      cc = __builtin_amdgcn_mfma_f32_16x16x32_f16(A1, Bp[c][1], cc, 0, 0, 0);
      const int col = 128 * w + 16 * c + n;
#pragma unroll
      for (int r = 0; r < 4; ++r) xpb[0][(4 * q + r) * XPS + col] = cc[r];
    }
  }
  hbuf[0][tid]       = (_Float16)0.f;
  hbuf[0][tid + 128] = (_Float16)0.f;
  __syncthreads();

  // ---- main recurrence: one 2-wave barrier per step
  int t = 0;
  for (int blk = 0; t < len; ++blk) {
    const int t0n = (blk + 1) * XPB;
    const bool havenext = t0n < len;
    float4 x0, x1, x2, x3;   // prefetch next block's x (stays in flight)
    if (havenext) {
      const float* pr = xb + (size_t)(t0n + n) * nI + 8 * q;
      x0 = *(const float4*)(pr);
      x1 = *(const float4*)(pr + 4);
      x2 = *(const float4*)(pr + 32);
      x3 = *(const float4*)(pr + 36);
    }

    const int nsteps = min(XPB, len - blk * XPB);
    const float* xpsrc = xpb[blk & 1];

    for (int s = 0; s < nsteps; ++s, ++t) {
      const _Float16* hsrc = hbuf[t & 1];

      // acc init = precomputed xp (+bias): 8 broadcast ds_read_b128
      f32x4 acc[8];
#pragma unroll
      for (int mt = 0; mt < 8; ++mt)
        acc[mt] = *(const f32x4*)(xpsrc + s * XPS + 128 * w + 16 * mt + 4 * q);

      // W_hh . h : 8 K-tiles x 8 M-tiles; 8 independent chains, depth 8
#pragma unroll
      for (int kt = 0; kt < 8; ++kt) {
        f16x8 Bh = *(const f16x8*)(hsrc + 32 * kt + 8 * q);
#pragma unroll
        for (int mt = 0; mt < 8; ++mt)
          acc[mt] = __builtin_amdgcn_mfma_f32_16x16x32_f16(Ah[mt][kt], Bh, acc[mt], 0, 0, 0);
      }

      // select this lane's owned pair: u = acc[n&7], regs {r0, r0+1}
      f32x4 s0 = (n & 1) ? acc[1] : acc[0];
      f32x4 s1 = (n & 1) ? acc[3] : acc[2];
      f32x4 s2 = (n & 1) ? acc[5] : acc[4];
      f32x4 s3 = (n & 1) ? acc[7] : acc[6];
      f32x4 t0v = (n & 2) ? s1 : s0;
      f32x4 t1v = (n & 2) ? s3 : s2;
      f32x4 u   = (n & 4) ? t1v : t0v;
      float va = (n & 8) ? u[2] : u[0];
      float vb = (n & 8) ? u[3] : u[1];
      float ha = fast_tanh(va);
      float hb = fast_tanh(vb);

      // produce next xp block during the last step of this block
      if (s == nsteps - 1 && havenext) {
        f16x8 A0 = { (_Float16)x0.x,(_Float16)x0.y,(_Float16)x0.z,(_Float16)x0.w,
                     (_Float16)x1.x,(_Float16)x1.y,(_Float16)x1.z,(_Float16)x1.w };
        f16x8 A1 = { (_Float16)x2.x,(_Float16)x2.y,(_Float16)x2.z,(_Float16)x2.w,
                     (_Float16)x3.x,(_Float16)x3.y,(_Float16)x3.z,(_Float16)x3.w };
        float* dst = xpb[(blk + 1) & 1];
#pragma unroll
        for (int c = 0; c < 8; ++c) {
          f32x4 cc = { biasp[c], biasp[c], biasp[c], biasp[c] };
          cc = __builtin_amdgcn_mfma_f32_16x16x32_f16(A0, Bp[c][0], cc, 0, 0, 0);
          cc = __builtin_amdgcn_mfma_f32_16x16x32_f16(A1, Bp[c][1], cc, 0, 0, 0);
          const int col = 128 * w + 16 * c + n;
#pragma unroll
          for (int r = 0; r < 4; ++r) dst[(4 * q + r) * XPS + col] = cc[r];
        }
      }

      // 2 packed f16 per lane -> one ds_write_b32; 128 lanes x 2 = full h
      *(f16x2*)&hbuf[(t + 1) & 1][own] = f16x2{ (_Float16)ha, (_Float16)hb };
      barrier_lgkm();
    }
  }

  // ---- epilogue: out[b] = h_final . W_fc + b_fc
  float v = (float)hbuf[len & 1][tid]       * Wfc[tid]
          + (float)hbuf[len & 1][tid + 128] * Wfc[tid + 128];
#pragma unroll
  for (int off = 32; off; off >>= 1) v += __shfl_down(v, off);
  if (l == 0) red[w] = v;
  __syncthreads();
  if (tid == 0) out[b] = red[0] + red[1] + bfc[0];
}

extern "C" void kernel_launch(void* const* d_in, const int* in_sizes, int n_in,
                              void* d_out, int out_size, void* d_ws, size_t ws_size,
                              hipStream_t stream) {
  const float* x   = (const float*)d_in[0];
  const int* lens  = (const int*)d_in[1];
  const float* Wih = (const float*)d_in[2];
  const float* Whh = (const float*)d_in[3];
  const float* bih = (const float*)d_in[4];
  const float* bhh = (const float*)d_in[5];
  const float* Wfc = (const float*)d_in[6];
  const float* bfc = (const float*)d_in[7];
  float* out = (float*)d_out;

  rnn_v5<<<nB, THREADS, 0, stream>>>(x, lens, Wih, Whh, bih, bhh, Wfc, bfc, out);
}

// Round 6
// 1948.585 us; speedup vs baseline: 1.1938x; 1.1938x over previous
//
#include <hip/hip_runtime.h>

// RNN B=256 T=2048 I=64 H=256 — Round 6: 4 SAMPLES PER WORKGROUP.
// The R2-family wall (~1370 cyc/step) is the LDS pipe: every wave reads the
// full-K B-fragments (8 x ds_read_b128 = 8KB) but with ONE sample the 16 MFMA
// columns are replicas -> 64KB/step of LDS traffic for 512B of unique h.
// Fix: columns carry 4 real samples (column group g = sample n&3), so one set
// of B reads serves 4 samples, and every C value is a distinct (row,sample)
// output. Column group n>>2 owns accumulator register r=n>>2 -> 4 tanh/lane,
// no select tree. 64 WGs x 256 thr (4 waves, 1/SIMD: per-CU DS drops to ~46
// instr/step; ILP = 16 indep MFMA chains covers latency). Weights resident in
// VGPR/AGPR A-frags; h + staged x in LDS f16 with bank-balanced strides;
// lgkm-only per-step barrier (global x prefetch stays in flight).

static constexpr int nT = 2048;
static constexpr int nI = 64;
static constexpr int nH = 256;
static constexpr int SAMP = 4;           // samples per WG
static constexpr int XBLK = 16;          // timesteps staged per chunk
static constexpr int HS = nH + 16;       // h sample stride (f16): 272 -> bank spread 8*s
static constexpr int XS = nI + 16;       // x sample stride (f16): 80  -> bank spread 8*s
static constexpr int XROW = SAMP * XS + 8; // x step stride (f16): 328 -> bank spread 4*s
static constexpr int THREADS = 256;      // 4 waves; wave w owns rows [64w,64w+64)

typedef _Float16 f16x8 __attribute__((ext_vector_type(8)));
typedef _Float16 f16x4 __attribute__((ext_vector_type(4)));
typedef float f32x4 __attribute__((ext_vector_type(4)));

__device__ __forceinline__ void barrier_lgkm() {
  asm volatile("s_waitcnt lgkmcnt(0)\n\ts_barrier" ::: "memory");
}

__device__ __forceinline__ float fast_tanh(float x) {
  float a = fabsf(x);
  float e = __expf(-2.0f * a);            // in (0,1], never overflows
  float r = (1.0f - e) / (1.0f + e);
  return copysignf(r, x);
}

__global__ __launch_bounds__(THREADS, 1)
void rnn_v6(const float* __restrict__ x, const int* __restrict__ lengths,
            const float* __restrict__ Wih, const float* __restrict__ Whh,
            const float* __restrict__ bih, const float* __restrict__ bhh,
            const float* __restrict__ Wfc, const float* __restrict__ bfc,
            float* __restrict__ out)
{
  __shared__ __align__(16) _Float16 hbuf[2][SAMP * HS];      // 4.3 KB
  __shared__ __align__(16) _Float16 hlast[SAMP * HS];        // 2.2 KB
  __shared__ __align__(16) _Float16 xbuf[2][XBLK * XROW];    // 21 KB

  const int b0  = blockIdx.x * SAMP;
  const int tid = threadIdx.x;
  const int w   = tid >> 6;       // wave 0..3 -> rows [64w, 64w+64)
  const int l   = tid & 63;
  const int q   = l >> 4;         // quad 0..3
  const int n   = l & 15;         // MFMA column lane
  const int sl  = n & 3;          // this lane's sample (column group)
  const int grp = n >> 2;         // this lane's owned accumulator register

  // lengths
  const int len0 = lengths[b0 + 0], len1 = lengths[b0 + 1];
  const int len2 = lengths[b0 + 2], len3 = lengths[b0 + 3];
  const int maxlen = max(max(len0, len1), max(len2, len3));
  const int mylen  = (sl == 0) ? len0 : (sl == 1) ? len1 : (sl == 2) ? len2 : len3;

  // ---- resident weights: A layout lane holds A[m=lane&15][k=8*(lane>>4)+j]
  f16x8 Ah[4][8];   // W_hh rows 64w+16mt+n, k = 32kt+8q+j   (128 regs)
  f16x8 Ax[4][2];   // W_ih rows, K=64 -> 2 k-tiles           (32 regs)
  f32x4 bias[4];    // rows 16mt*...: reg r <-> row 64w+16mt+4q+r (col-indep)
#pragma unroll
  for (int mt = 0; mt < 4; ++mt) {
    const int row = 64 * w + 16 * mt + n;
#pragma unroll
    for (int kt = 0; kt < 8; ++kt) {
      const float* src = Whh + row * nH + 32 * kt + 8 * q;
      f16x8 a;
#pragma unroll
      for (int j = 0; j < 8; ++j) a[j] = (_Float16)src[j];
      Ah[mt][kt] = a;
    }
#pragma unroll
    for (int kt = 0; kt < 2; ++kt) {
      const float* src = Wih + row * nI + 32 * kt + 8 * q;
      f16x8 a;
#pragma unroll
      for (int j = 0; j < 8; ++j) a[j] = (_Float16)src[j];
      Ax[mt][kt] = a;
    }
#pragma unroll
    for (int r = 0; r < 4; ++r) {
      const int rr = 64 * w + 16 * mt + 4 * q + r;
      bias[mt][r] = bih[rr] + bhh[rr];
    }
  }

  // ---- h0 = 0; stage x chunk 0 (thread -> step s=tid>>4, i-quad (tid&15)*4)
#pragma unroll
  for (int sp = 0; sp < SAMP; ++sp) hbuf[0][sp * HS + tid] = (_Float16)0.f;
  {
    const int s_thr = tid >> 4;
    const int i4    = (tid & 15) * 4;
#pragma unroll
    for (int sp = 0; sp < SAMP; ++sp) {
      float4 v = *(const float4*)(x + ((size_t)(b0 + sp) * nT + s_thr) * nI + i4);
      *(f16x4*)&xbuf[0][s_thr * XROW + sp * XS + i4] =
          f16x4{ (_Float16)v.x, (_Float16)v.y, (_Float16)v.z, (_Float16)v.w };
    }
  }
  __syncthreads();

  // ---- main recurrence
  int t = 0;
  for (int blk = 0; t < maxlen; ++blk) {
    const int t0n = (blk + 1) * XBLK;
    const bool havenext = t0n < maxlen;
    float4 pre[SAMP];               // next chunk's x, in flight across barriers
    const int s_thr = tid >> 4;
    const int i4    = (tid & 15) * 4;
    if (havenext) {
#pragma unroll
      for (int sp = 0; sp < SAMP; ++sp)
        pre[sp] = *(const float4*)(x + ((size_t)(b0 + sp) * nT + t0n + s_thr) * nI + i4);
    }

    const int nsteps = min(XBLK, maxlen - blk * XBLK);
    const _Float16* xc = xbuf[blk & 1];

    for (int s = 0; s < nsteps; ++s, ++t) {
      const _Float16* hsrc = hbuf[t & 1];
      _Float16*       hdst = hbuf[(t + 1) & 1];

      f32x4 acc0 = bias[0], acc1 = bias[1], acc2 = bias[2], acc3 = bias[3];

      // W_hh . h : 8 k-tiles; B[k][n] = h[sample n&3][32kt+8q+j] (4-lane bcast)
#pragma unroll
      for (int kt = 0; kt < 8; ++kt) {
        f16x8 Bh = *(const f16x8*)(hsrc + sl * HS + 32 * kt + 8 * q);
        acc0 = __builtin_amdgcn_mfma_f32_16x16x32_f16(Ah[0][kt], Bh, acc0, 0, 0, 0);
        acc1 = __builtin_amdgcn_mfma_f32_16x16x32_f16(Ah[1][kt], Bh, acc1, 0, 0, 0);
        acc2 = __builtin_amdgcn_mfma_f32_16x16x32_f16(Ah[2][kt], Bh, acc2, 0, 0, 0);
        acc3 = __builtin_amdgcn_mfma_f32_16x16x32_f16(Ah[3][kt], Bh, acc3, 0, 0, 0);
      }
      // W_ih . x_t : 2 k-tiles from staged x (4-lane bcast)
#pragma unroll
      for (int kt = 0; kt < 2; ++kt) {
        f16x8 Bx = *(const f16x8*)(xc + s * XROW + sl * XS + 32 * kt + 8 * q);
        acc0 = __builtin_amdgcn_mfma_f32_16x16x32_f16(Ax[0][kt], Bx, acc0, 0, 0, 0);
        acc1 = __builtin_amdgcn_mfma_f32_16x16x32_f16(Ax[1][kt], Bx, acc1, 0, 0, 0);
        acc2 = __builtin_amdgcn_mfma_f32_16x16x32_f16(Ax[2][kt], Bx, acc2, 0, 0, 0);
        acc3 = __builtin_amdgcn_mfma_f32_16x16x32_f16(Ax[3][kt], Bx, acc3, 0, 0, 0);
      }

      // column group g = n>>2 owns register r=g: 4 tanh/lane, all distinct
      // (row = 64w+16mt+4q+grp, sample = sl)
      float v0, v1, v2, v3;
      {
        float a01 = (grp & 1) ? acc0[1] : acc0[0];
        float a23 = (grp & 1) ? acc0[3] : acc0[2];
        v0 = (grp & 2) ? a23 : a01;
        a01 = (grp & 1) ? acc1[1] : acc1[0];
        a23 = (grp & 1) ? acc1[3] : acc1[2];
        v1 = (grp & 2) ? a23 : a01;
        a01 = (grp & 1) ? acc2[1] : acc2[0];
        a23 = (grp & 1) ? acc2[3] : acc2[2];
        v2 = (grp & 2) ? a23 : a01;
        a01 = (grp & 1) ? acc3[1] : acc3[0];
        a23 = (grp & 1) ? acc3[3] : acc3[2];
        v3 = (grp & 2) ? a23 : a01;
      }
      const _Float16 h0 = (_Float16)fast_tanh(v0);
      const _Float16 h1 = (_Float16)fast_tanh(v1);
      const _Float16 h2 = (_Float16)fast_tanh(v2);
      const _Float16 h3 = (_Float16)fast_tanh(v3);

      const int rbase = 64 * w + 4 * q + grp;
      hdst[sl * HS + rbase]      = h0;
      hdst[sl * HS + rbase + 16] = h1;
      hdst[sl * HS + rbase + 32] = h2;
      hdst[sl * HS + rbase + 48] = h3;

      if (t + 1 == mylen) {       // capture this sample's final h
        hlast[sl * HS + rbase]      = h0;
        hlast[sl * HS + rbase + 16] = h1;
        hlast[sl * HS + rbase + 32] = h2;
        hlast[sl * HS + rbase + 48] = h3;
      }

      // fold next-chunk staging writes in before this chunk's last barrier
      if (s == nsteps - 1 && havenext) {
        _Float16* xd = xbuf[(blk + 1) & 1];
#pragma unroll
        for (int sp = 0; sp < SAMP; ++sp)
          *(f16x4*)&xd[s_thr * XROW + sp * XS + i4] =
              f16x4{ (_Float16)pre[sp].x, (_Float16)pre[sp].y,
                     (_Float16)pre[sp].z, (_Float16)pre[sp].w };
      }

      barrier_lgkm();
    }
  }

  // ---- epilogue: wave w reduces sample w: out[b0+w] = hlast[w] . W_fc + b_fc
  __syncthreads();
  {
    float v = 0.f;
#pragma unroll
    for (int j = 0; j < 4; ++j) {
      const int row = l + 64 * j;
      v += (float)hlast[w * HS + row] * Wfc[row];
    }
#pragma unroll
    for (int off = 32; off; off >>= 1) v += __shfl_down(v, off);
    if (l == 0) out[b0 + w] = v + bfc[0];
  }
}

extern "C" void kernel_launch(void* const* d_in, const int* in_sizes, int n_in,
                              void* d_out, int out_size, void* d_ws, size_t ws_size,
                              hipStream_t stream) {
  const float* x   = (const float*)d_in[0];
  const int* lens  = (const int*)d_in[1];
  const float* Wih = (const float*)d_in[2];
  const float* Whh = (const float*)d_in[3];
  const float* bih = (const float*)d_in[4];
  const float* bhh = (const float*)d_in[5];
  const float* Wfc = (const float*)d_in[6];
  const float* bfc = (const float*)d_in[7];
  float* out = (float*)d_out;

  rnn_v6<<<256 / SAMP, THREADS, 0, stream>>>(x, lens, Wih, Whh, bih, bhh, Wfc, bfc, out);
}